// Round 1
// baseline (290.164 us; speedup 1.0000x reference)
//
#include <hip/hip_runtime.h>
#include <math.h>

#define NEI 15

// ---------------------------------------------------------------------------
// Kernel 1: scan the dense adjacency matrix (float32), collect nonzero column
// indices per row (unordered) via per-row atomic counters.
// ---------------------------------------------------------------------------
__global__ void find_nb_kernel(const float* __restrict__ A,
                               int* __restrict__ cnt,
                               int* __restrict__ nb,
                               int N, long long total) {
    const long long total4 = total >> 2;           // float4 count
    const long long stride = (long long)gridDim.x * blockDim.x;
    long long t = (long long)blockIdx.x * blockDim.x + threadIdx.x;
    for (; t < total4; t += stride) {
        const float4 v = reinterpret_cast<const float4*>(A)[t];
        if (v.x != 0.f || v.y != 0.f || v.z != 0.f || v.w != 0.f) {
            const long long e = t << 2;
            float vals[4] = {v.x, v.y, v.z, v.w};
            #pragma unroll
            for (int q = 0; q < 4; ++q) {
                if (vals[q] != 0.f) {
                    const long long ee = e + q;
                    const int row = (int)(ee / N);
                    const int col = (int)(ee - (long long)row * N);
                    const int p = atomicAdd(&cnt[row], 1);
                    if (p < NEI) nb[row * NEI + p] = col;
                }
            }
        }
    }
    // tail elements (if total not divisible by 4)
    const long long tail_start = total4 << 2;
    for (long long ee = tail_start + (long long)blockIdx.x * blockDim.x + threadIdx.x;
         ee < total; ee += stride) {
        if (A[ee] != 0.f) {
            const int row = (int)(ee / N);
            const int col = (int)(ee - (long long)row * N);
            const int p = atomicAdd(&cnt[row], 1);
            if (p < NEI) nb[row * NEI + p] = col;
        }
    }
}

// ---------------------------------------------------------------------------
// Kernel 2: insertion-sort each row's neighbor list ascending (deterministic
// regardless of atomic arrival order).
// ---------------------------------------------------------------------------
__global__ void sort_nb_kernel(int* __restrict__ nb, int N) {
    const int i = blockIdx.x * blockDim.x + threadIdx.x;
    if (i >= N) return;
    int v[NEI];
    #pragma unroll
    for (int q = 0; q < NEI; ++q) v[q] = nb[i * NEI + q];
    #pragma unroll
    for (int a = 1; a < NEI; ++a) {
        const int key = v[a];
        int b = a - 1;
        while (b >= 0 && v[b] > key) { v[b + 1] = v[b]; --b; }
        v[b + 1] = key;
    }
    #pragma unroll
    for (int q = 0; q < NEI; ++q) nb[i * NEI + q] = v[q];
}

// ---------------------------------------------------------------------------
// Kernel 3: count triangles with minimum vertex i.
// Neighbors sorted ascending; for pairs a=v[j] < b=v[k], both > i, test b in
// nb1[a].
// ---------------------------------------------------------------------------
__global__ void count_tri_kernel(const int* __restrict__ nb,
                                 int* __restrict__ tricnt, int N) {
    const int i = blockIdx.x * blockDim.x + threadIdx.x;
    if (i >= N) return;
    int v[NEI];
    #pragma unroll
    for (int q = 0; q < NEI; ++q) v[q] = nb[i * NEI + q];
    int c = 0;
    for (int j = 0; j < NEI; ++j) {
        const int a = v[j];
        if (a <= i) continue;
        const int* na = &nb[a * NEI];
        int adjmask_count = 0;
        for (int k = j + 1; k < NEI; ++k) {
            const int b = v[k];
            bool adj = false;
            #pragma unroll
            for (int q = 0; q < NEI; ++q) adj = adj || (na[q] == b);
            adjmask_count += adj ? 1 : 0;
        }
        c += adjmask_count;
    }
    tricnt[i] = c;
}

// ---------------------------------------------------------------------------
// Kernel 4: single-block exclusive prefix sum over tricnt -> offs[0..N].
// ---------------------------------------------------------------------------
__global__ void scan_kernel(const int* __restrict__ tricnt,
                            int* __restrict__ offs, int N) {
    __shared__ int partial[1024];
    const int tid = threadIdx.x;
    const int per = (N + 1023) / 1024;
    const int start = tid * per;
    int sum = 0;
    for (int q = 0; q < per; ++q) {
        const int idx = start + q;
        if (idx < N) sum += tricnt[idx];
    }
    partial[tid] = sum;
    __syncthreads();
    // Hillis-Steele inclusive scan over the 1024 partials
    for (int d = 1; d < 1024; d <<= 1) {
        const int mine  = partial[tid];
        const int other = (tid >= d) ? partial[tid - d] : 0;
        __syncthreads();
        partial[tid] = mine + other;
        __syncthreads();
    }
    int run = (tid == 0) ? 0 : partial[tid - 1];
    for (int q = 0; q < per; ++q) {
        const int idx = start + q;
        if (idx < N) { offs[idx] = run; run += tricnt[idx]; }
    }
    if (tid == 1023) offs[N] = run;
}

// ---------------------------------------------------------------------------
// Kernel 5: emit triangles (i, a, b) in global lexicographic order.
// ---------------------------------------------------------------------------
__global__ void emit_tri_kernel(const int* __restrict__ nb,
                                const int* __restrict__ offs,
                                int* __restrict__ out, int N) {
    const int i = blockIdx.x * blockDim.x + threadIdx.x;
    if (i >= N) return;
    int v[NEI];
    #pragma unroll
    for (int q = 0; q < NEI; ++q) v[q] = nb[i * NEI + q];
    int pos = offs[i];
    for (int j = 0; j < NEI; ++j) {
        const int a = v[j];
        if (a <= i) continue;
        const int* na = &nb[a * NEI];
        for (int k = j + 1; k < NEI; ++k) {
            const int b = v[k];
            bool adj = false;
            #pragma unroll
            for (int q = 0; q < NEI; ++q) adj = adj || (na[q] == b);
            if (adj) {
                out[3 * pos + 0] = i;
                out[3 * pos + 1] = a;
                out[3 * pos + 2] = b;
                ++pos;
            }
        }
    }
}

extern "C" void kernel_launch(void* const* d_in, const int* in_sizes, int n_in,
                              void* d_out, int out_size, void* d_ws, size_t ws_size,
                              hipStream_t stream) {
    const float* A = (const float*)d_in[0];
    const long long total = (long long)in_sizes[0];
    const int N = (int)llround(sqrt((double)total));

    int* ws = (int*)d_ws;
    // Workspace layout (ints): cnt[N] | nb[N*15] | tricnt[N] | offs[N+1]
    int* w_cnt    = ws;
    int* w_nb     = ws + N;
    int* w_tricnt = ws + N + N * NEI;
    int* w_offs   = ws + N + N * NEI + N;

    int* out = (int*)d_out;

    // zero the per-row atomic counters (only state that needs re-init)
    hipMemsetAsync(w_cnt, 0, (size_t)N * sizeof(int), stream);

    // 1) scan adjacency for nonzero columns
    {
        const int threads = 256;
        const int blocks = 2048;
        find_nb_kernel<<<blocks, threads, 0, stream>>>(A, w_cnt, w_nb, N, total);
    }
    // 2) sort each neighbor list
    {
        const int threads = 256;
        const int blocks = (N + threads - 1) / threads;
        sort_nb_kernel<<<blocks, threads, 0, stream>>>(w_nb, N);
    }
    // 3) count triangles per minimum vertex
    {
        const int threads = 256;
        const int blocks = (N + threads - 1) / threads;
        count_tri_kernel<<<blocks, threads, 0, stream>>>(w_nb, w_tricnt, N);
    }
    // 4) prefix sum
    scan_kernel<<<1, 1024, 0, stream>>>(w_tricnt, w_offs, N);
    // 5) emit in lexicographic order
    {
        const int threads = 256;
        const int blocks = (N + threads - 1) / threads;
        emit_tri_kernel<<<blocks, threads, 0, stream>>>(w_nb, w_offs, out, N);
    }
}